// Round 7
// baseline (684.583 us; speedup 1.0000x reference)
//
#include <hip/hip_runtime.h>

#define NUSERS 100000
#define NITEMS 50000
#define NNODES (NUSERS + NITEMS)
#define DIM 64
#define NEDGE 2000000

// bucketed edge build
#define BSH 7                       // 128 dst nodes per bucket
#define NB ((NNODES + 127) >> BSH)  // 1172 buckets
#define CAP 2048                    // per-bucket region capacity (mean 1707, sd 41 -> 8.3 sigma)
#define CHUNK 4096                  // edges per bucket_kernel block (measured-good config)
#define ABLOCKS ((NEDGE + CHUNK - 1) / CHUNK)  // 489

// ---------------------------------------------------------------------------
// Phase A: block-level counting sort of a 4096-edge chunk into 1172 coarse
// dst-buckets (dst>>7). Record = 8B: (src | (dst&127)<<18, w_bits).
// Unchanged (measured-good).
// ---------------------------------------------------------------------------
__global__ __launch_bounds__(256)
void bucket_kernel(const int* __restrict__ eidx, const float* __restrict__ ew,
                   int* __restrict__ gcur, int2* __restrict__ regions) {
    __shared__ int cursor_s[NB];          // histogram, then LDS staging cursor
    __shared__ int excl_s[NB];            // block-local exclusive offsets
    __shared__ int gbase_s[NB];           // reserved base inside bucket region
    __shared__ int scanbuf[256];
    __shared__ int2 stage[CHUNK];         // 32 KB
    __shared__ unsigned short sbkt[CHUNK];// 8 KB

    const int t = threadIdx.x;
    const int e0 = blockIdx.x * CHUNK;
    const int cnt_edges = min(CHUNK, NEDGE - e0);   // always multiple of 4

    for (int i = t; i < NB; i += 256) cursor_s[i] = 0;
    __syncthreads();

    // pass 1: load 16 edges/thread (int4/float4 coalesced), LDS histogram
    int2 recs[16];
    int bk[16];
    const int e4base = e0 >> 2;
#pragma unroll
    for (int k = 0; k < 4; ++k) {
        int g = k * 256 + t;                       // 4-edge group within chunk
        bool ok = (4 * g) < cnt_edges;
        int4 s4 = make_int4(0, 0, 0, 0), d4 = make_int4(0, 0, 0, 0);
        float4 w4 = make_float4(0.f, 0.f, 0.f, 0.f);
        if (ok) {
            int e4 = e4base + g;
            s4 = ((const int4*)eidx)[e4];
            d4 = ((const int4*)eidx)[(NEDGE >> 2) + e4];
            w4 = ((const float4*)ew)[e4];
        }
        int ss[4] = {s4.x, s4.y, s4.z, s4.w};
        int dd[4] = {d4.x, d4.y, d4.z, d4.w};
        float ww[4] = {w4.x, w4.y, w4.z, w4.w};
#pragma unroll
        for (int j = 0; j < 4; ++j) {
            int idx = 4 * k + j;
            if (ok) {
                int d = dd[j];
                int b = d >> BSH;
                bk[idx] = b;
                recs[idx].x = ss[j] | ((d & 127) << 18);   // src < 2^18
                recs[idx].y = __float_as_int(ww[j]);
                atomicAdd(&cursor_s[b], 1);
            } else {
                bk[idx] = -1;
            }
        }
    }
    __syncthreads();

    // block scan of the 1172 counts; thread t owns [5t, 5t+5)
    int myv[5];
    int tsum = 0;
    const int base_i = t * 5;
#pragma unroll
    for (int j = 0; j < 5; ++j) {
        int i = base_i + j;
        myv[j] = (i < NB) ? cursor_s[i] : 0;
        tsum += myv[j];
    }
    scanbuf[t] = tsum;
    __syncthreads();
    for (int d = 1; d < 256; d <<= 1) {
        int u = (t >= d) ? scanbuf[t - d] : 0;
        __syncthreads();
        scanbuf[t] += u;
        __syncthreads();
    }
    int run = scanbuf[t] - tsum;   // exclusive base of this thread's range
#pragma unroll
    for (int j = 0; j < 5; ++j) {
        int i = base_i + j;
        if (i < NB) {
            excl_s[i] = run;
            cursor_s[i] = run;     // becomes staging cursor
            if (myv[j] > 0) gbase_s[i] = atomicAdd(&gcur[i], myv[j]);
            run += myv[j];
        }
    }
    __syncthreads();

    // pass 2: counting-sort into LDS staging
#pragma unroll
    for (int k = 0; k < 16; ++k) {
        if (bk[k] >= 0) {
            int p = atomicAdd(&cursor_s[bk[k]], 1);
            stage[p] = recs[k];
            sbkt[p] = (unsigned short)bk[k];
        }
    }
    __syncthreads();

    // pass 3: coalesced write-out of per-bucket runs
    for (int i = t; i < cnt_edges; i += 256) {
        int b = sbkt[i];
        int gpos = gbase_s[b] + (i - excl_s[b]);
        if (gpos < CAP) regions[(long)b * CAP + gpos] = stage[i];
    }
}

// ---------------------------------------------------------------------------
// sort + pull layer 1: one block (512 thr) per 128-node bucket.
//  (a) sort the bucket's records by local dst in LDS (hist+scan+scatter)
//  (b) write sorted records + per-node (start,end) for pull2 (coalesced)
//  (c) per-node-wave pull reading records from LDS, gathering rows straight
//      from eu/eit. Fused ReLU. (measured: 104 us)
// ---------------------------------------------------------------------------
__global__ __launch_bounds__(512)
void sortpull1_kernel(const int* __restrict__ gcur, const int2* __restrict__ regions,
                      const float* __restrict__ eu, const float* __restrict__ eit,
                      int2* __restrict__ edge_sorted, int2* __restrict__ rs,
                      float* __restrict__ buf1) {
    __shared__ int2 srec[CAP];        // 16 KB sorted records
    __shared__ int cnt[128];          // hist, then scatter cursor
    __shared__ int excl[128];         // per-node start (local)
    __shared__ int scanbuf[128];
    const int t = threadIdx.x;
    const int b = blockIdx.x;
    const int node0 = b << BSH;
    const int ecnt = min(gcur[b], CAP);
    const long gbase = (long)b * CAP;

    if (t < 128) cnt[t] = 0;
    __syncthreads();

    // load raw records to registers + LDS histogram (1 scalar atomic/record)
    int2 recs[4];
#pragma unroll
    for (int k = 0; k < 4; ++k) {
        int i = k * 512 + t;
        if (i < ecnt) {
            recs[k] = regions[gbase + i];
            atomicAdd(&cnt[(recs[k].x >> 18) & 127], 1);
        }
    }
    __syncthreads();

    // scan of 128 counts
    if (t < 128) scanbuf[t] = cnt[t];
    __syncthreads();
    for (int d = 1; d < 128; d <<= 1) {
        int u = 0;
        if (t < 128 && t >= d) u = scanbuf[t - d];
        __syncthreads();
        if (t < 128) scanbuf[t] += u;
        __syncthreads();
    }
    if (t < 128) {
        excl[t] = scanbuf[t] - cnt[t];
        cnt[t] = scanbuf[t] - cnt[t];   // cursor = excl
    }
    __syncthreads();

    // scatter into sorted LDS array (clean src while at it)
#pragma unroll
    for (int k = 0; k < 4; ++k) {
        int i = k * 512 + t;
        if (i < ecnt) {
            int d = (recs[k].x >> 18) & 127;
            int p = atomicAdd(&cnt[d], 1);
            int2 o;
            o.x = recs[k].x & 0x3FFFF;
            o.y = recs[k].y;
            srec[p] = o;
        }
    }
    __syncthreads();
    // cnt[] now holds per-node END (exclusive), excl[] holds START

    // write-through for pull2: sorted records (coalesced) + (start,end) pairs
    for (int i = t; i < ecnt; i += 512) edge_sorted[gbase + i] = srec[i];
    if (t < 128) {
        int node = node0 + t;
        if (node < NNODES) {
            int2 p;
            p.x = (int)gbase + excl[t];
            p.y = (int)gbase + cnt[t];
            rs[node] = p;
        }
    }

    // per-node-wave pull from LDS records
    const int lane = t & 63;
    const int wv = t >> 6;                 // 0..7
#pragma unroll 1
    for (int j = 0; j < 16; ++j) {
        const int local = wv * 16 + j;
        const int node = node0 + local;
        if (node >= NNODES) break;         // wave-uniform
        int i = excl[local];
        const int iend = cnt[local];
        float a0 = 0.f, a1 = 0.f, a2 = 0.f, a3 = 0.f;
        for (; i + 3 < iend; i += 4) {
            int2 r0 = srec[i + 0], r1 = srec[i + 1], r2 = srec[i + 2], r3 = srec[i + 3];
            const float* p0 = (r0.x < NUSERS) ? (eu + ((long)r0.x << 6)) : (eit + ((long)(r0.x - NUSERS) << 6));
            const float* p1 = (r1.x < NUSERS) ? (eu + ((long)r1.x << 6)) : (eit + ((long)(r1.x - NUSERS) << 6));
            const float* p2 = (r2.x < NUSERS) ? (eu + ((long)r2.x << 6)) : (eit + ((long)(r2.x - NUSERS) << 6));
            const float* p3 = (r3.x < NUSERS) ? (eu + ((long)r3.x << 6)) : (eit + ((long)(r3.x - NUSERS) << 6));
            float v0 = p0[lane], v1 = p1[lane], v2 = p2[lane], v3 = p3[lane];
            a0 = fmaf(__int_as_float(r0.y), v0, a0);
            a1 = fmaf(__int_as_float(r1.y), v1, a1);
            a2 = fmaf(__int_as_float(r2.y), v2, a2);
            a3 = fmaf(__int_as_float(r3.y), v3, a3);
        }
        for (; i < iend; ++i) {
            int2 r = srec[i];
            const float* p = (r.x < NUSERS) ? (eu + ((long)r.x << 6)) : (eit + ((long)(r.x - NUSERS) << 6));
            a0 = fmaf(__int_as_float(r.y), p[lane], a0);
        }
        buf1[((long)node << 6) + lane] = fmaxf((a0 + a1) + (a2 + a3), 0.f);
    }
}

// ---------------------------------------------------------------------------
// pull layer 2 + fused epilogue, v2: one wave per node (pull2's measured-good
// structure, VGPR-light). Epilogue per node:
//   x = (e0+e1+e2)/3 -> LDS bounce xtile[wv] (1 KB, same-wave RAW, no barrier)
//   y[lane] = sum_k x[k] * W[lane][k]: x via float4 same-address broadcast,
//   W streamed as 16 float4 L1-hit loads per node (W is 16 KB, L1-resident).
// No wreg array, no shuffles, no __syncthreads. Writes final + copy rows.
// ---------------------------------------------------------------------------
__global__ __launch_bounds__(256)
void pull2final_kernel(const int2* __restrict__ rs,
                       const int2* __restrict__ edge_sorted,
                       const float* __restrict__ buf1,
                       const float* __restrict__ eu, const float* __restrict__ eit,
                       const float* __restrict__ W, const float* __restrict__ bias,
                       float* __restrict__ out) {
    __shared__ float xtile[4][64];       // per-wave x row
    const int lane = threadIdx.x & 63;
    const int wv = threadIdx.x >> 6;
    const int n = (int)((blockIdx.x * (long)blockDim.x + threadIdx.x) >> 6);
    if (n >= NNODES) return;

    int2 be = rs[n];
    int i = be.x;
    const int e2 = be.y;
    float sa = 0.f, sb = 0.f;
    for (; i + 3 < e2; i += 4) {
        int2 r0 = edge_sorted[i],     r1 = edge_sorted[i + 1];
        int2 r2 = edge_sorted[i + 2], r3 = edge_sorted[i + 3];
        float v0 = buf1[(long)r0.x * DIM + lane];
        float v1 = buf1[(long)r1.x * DIM + lane];
        float v2 = buf1[(long)r2.x * DIM + lane];
        float v3 = buf1[(long)r3.x * DIM + lane];
        sa = fmaf(__int_as_float(r0.y), v0, sa);
        sb = fmaf(__int_as_float(r1.y), v1, sb);
        sa = fmaf(__int_as_float(r2.y), v2, sa);
        sb = fmaf(__int_as_float(r3.y), v3, sb);
    }
    for (; i < e2; ++i) {
        int2 r = edge_sorted[i];
        sa = fmaf(__int_as_float(r.y), buf1[(long)r.x * DIM + lane], sa);
    }
    float e2v = fmaxf(sa + sb, 0.f);

    // e0 / e1 rows (coalesced)
    const float* e0p = (n < NUSERS) ? (eu + ((long)n << 6))
                                    : (eit + ((long)(n - NUSERS) << 6));
    float e0v = e0p[lane];
    float e1v = buf1[((long)n << 6) + lane];
    float xsum = e0v + e1v + e2v;        // scale by 1/3 after the dot product

    // LDS bounce: stage x row, read back as float4 broadcasts (same wave)
    xtile[wv][lane] = xsum;
    const float4* xr = (const float4*)xtile[wv];
    const float4* Wr = (const float4*)(W + ((long)lane << 6));   // lane's W row
    float s0 = 0.f, s1 = 0.f;
#pragma unroll
    for (int k = 0; k < 16; ++k) {
        float4 wq = Wr[k];               // L1-hit (W is 16 KB, resident)
        float4 xv = xr[k];               // LDS same-address broadcast
        s0 = fmaf(xv.x, wq.x, s0);
        s1 = fmaf(xv.y, wq.y, s1);
        s0 = fmaf(xv.z, wq.z, s0);
        s1 = fmaf(xv.w, wq.w, s1);
    }
    float val = fmaf(s0 + s1, (1.0f / 3.0f), bias[lane]);

    long fo, co;
    if (n < NUSERS) {
        fo = (long)n * DIM;
        co = fo + (long)NUSERS * DIM;
    } else {
        fo = (long)2 * NUSERS * DIM + (long)(n - NUSERS) * DIM;
        co = fo + (long)NITEMS * DIM;
    }
    out[fo + lane] = val;
    out[co + lane] = e0v;                // pass-through copy
}

extern "C" void kernel_launch(void* const* d_in, const int* in_sizes, int n_in,
                              void* d_out, int out_size, void* d_ws, size_t ws_size,
                              hipStream_t stream) {
    const int*   eidx = (const int*)d_in[0];     // (2, E) int
    const float* ew   = (const float*)d_in[1];   // (E,)
    const float* eu   = (const float*)d_in[2];   // (NUSERS, 64)
    const float* eit  = (const float*)d_in[3];   // (NITEMS, 64)
    const float* W    = (const float*)d_in[4];   // (64, 64)
    const float* bias = (const float*)d_in[5];   // (64,)
    float* out = (float*)d_out;

    const size_t nfeat = (size_t)NNODES * DIM;   // 9.6M floats
    float* buf1        = (float*)d_ws;                           // 38.4 MB
    int2*  regions     = (int2*)(buf1 + nfeat);                  // 19.2 MB
    int2*  edge_sorted = regions + (long)NB * CAP;               // 19.2 MB
    int2*  rs          = edge_sorted + (long)NB * CAP;           // 1.2 MB
    int*   gcur        = (int*)(rs + NNODES);

    const int nodeWaveBlocks = (NNODES * 64 + 255) / 256;        // 37500

    hipMemsetAsync(gcur, 0, NB * sizeof(int), stream);

    // single-pass bucketed edge build
    bucket_kernel<<<ABLOCKS, 256, 0, stream>>>(eidx, ew, gcur, regions);

    // sort-in-LDS + layer-1 pull
    sortpull1_kernel<<<NB, 512, 0, stream>>>(gcur, regions, eu, eit,
                                             edge_sorted, rs, buf1);

    // layer 2 + fused epilogue (LDS-bounce broadcast; final_kernel + buf2 gone)
    pull2final_kernel<<<nodeWaveBlocks, 256, 0, stream>>>(rs, edge_sorted, buf1,
                                                          eu, eit, W, bias, out);
}

// Round 8
// 408.883 us; speedup vs baseline: 1.6743x; 1.6743x over previous
//
#include <hip/hip_runtime.h>

#define NUSERS 100000
#define NITEMS 50000
#define NNODES (NUSERS + NITEMS)
#define DIM 64
#define NEDGE 2000000
#define FT_ROWS 128
#define FT_BLOCKS ((NNODES + FT_ROWS - 1) / FT_ROWS)   // 1172

// bucketed edge build
#define BSH 7                       // 128 dst nodes per bucket
#define NB ((NNODES + 127) >> BSH)  // 1172 buckets
#define CAP 2048                    // per-bucket region capacity (mean 1707, sd 41 -> 8.3 sigma)
#define CHUNK 4096                  // edges per bucket_kernel block (measured-good config)
#define ABLOCKS ((NEDGE + CHUNK - 1) / CHUNK)  // 489

// ---------------------------------------------------------------------------
// Phase A: block-level counting sort of a 4096-edge chunk into 1172 coarse
// dst-buckets (dst>>7). Record = 8B: (src | (dst&127)<<18, w_bits).
// Unchanged (measured-good).
// ---------------------------------------------------------------------------
__global__ __launch_bounds__(256)
void bucket_kernel(const int* __restrict__ eidx, const float* __restrict__ ew,
                   int* __restrict__ gcur, int2* __restrict__ regions) {
    __shared__ int cursor_s[NB];          // histogram, then LDS staging cursor
    __shared__ int excl_s[NB];            // block-local exclusive offsets
    __shared__ int gbase_s[NB];           // reserved base inside bucket region
    __shared__ int scanbuf[256];
    __shared__ int2 stage[CHUNK];         // 32 KB
    __shared__ unsigned short sbkt[CHUNK];// 8 KB

    const int t = threadIdx.x;
    const int e0 = blockIdx.x * CHUNK;
    const int cnt_edges = min(CHUNK, NEDGE - e0);   // always multiple of 4

    for (int i = t; i < NB; i += 256) cursor_s[i] = 0;
    __syncthreads();

    // pass 1: load 16 edges/thread (int4/float4 coalesced), LDS histogram
    int2 recs[16];
    int bk[16];
    const int e4base = e0 >> 2;
#pragma unroll
    for (int k = 0; k < 4; ++k) {
        int g = k * 256 + t;                       // 4-edge group within chunk
        bool ok = (4 * g) < cnt_edges;
        int4 s4 = make_int4(0, 0, 0, 0), d4 = make_int4(0, 0, 0, 0);
        float4 w4 = make_float4(0.f, 0.f, 0.f, 0.f);
        if (ok) {
            int e4 = e4base + g;
            s4 = ((const int4*)eidx)[e4];
            d4 = ((const int4*)eidx)[(NEDGE >> 2) + e4];
            w4 = ((const float4*)ew)[e4];
        }
        int ss[4] = {s4.x, s4.y, s4.z, s4.w};
        int dd[4] = {d4.x, d4.y, d4.z, d4.w};
        float ww[4] = {w4.x, w4.y, w4.z, w4.w};
#pragma unroll
        for (int j = 0; j < 4; ++j) {
            int idx = 4 * k + j;
            if (ok) {
                int d = dd[j];
                int b = d >> BSH;
                bk[idx] = b;
                recs[idx].x = ss[j] | ((d & 127) << 18);   // src < 2^18
                recs[idx].y = __float_as_int(ww[j]);
                atomicAdd(&cursor_s[b], 1);
            } else {
                bk[idx] = -1;
            }
        }
    }
    __syncthreads();

    // block scan of the 1172 counts; thread t owns [5t, 5t+5)
    int myv[5];
    int tsum = 0;
    const int base_i = t * 5;
#pragma unroll
    for (int j = 0; j < 5; ++j) {
        int i = base_i + j;
        myv[j] = (i < NB) ? cursor_s[i] : 0;
        tsum += myv[j];
    }
    scanbuf[t] = tsum;
    __syncthreads();
    for (int d = 1; d < 256; d <<= 1) {
        int u = (t >= d) ? scanbuf[t - d] : 0;
        __syncthreads();
        scanbuf[t] += u;
        __syncthreads();
    }
    int run = scanbuf[t] - tsum;   // exclusive base of this thread's range
#pragma unroll
    for (int j = 0; j < 5; ++j) {
        int i = base_i + j;
        if (i < NB) {
            excl_s[i] = run;
            cursor_s[i] = run;     // becomes staging cursor
            if (myv[j] > 0) gbase_s[i] = atomicAdd(&gcur[i], myv[j]);
            run += myv[j];
        }
    }
    __syncthreads();

    // pass 2: counting-sort into LDS staging
#pragma unroll
    for (int k = 0; k < 16; ++k) {
        if (bk[k] >= 0) {
            int p = atomicAdd(&cursor_s[bk[k]], 1);
            stage[p] = recs[k];
            sbkt[p] = (unsigned short)bk[k];
        }
    }
    __syncthreads();

    // pass 3: coalesced write-out of per-bucket runs
    for (int i = t; i < cnt_edges; i += 256) {
        int b = sbkt[i];
        int gpos = gbase_s[b] + (i - excl_s[b]);
        if (gpos < CAP) regions[(long)b * CAP + gpos] = stage[i];
    }
}

// ---------------------------------------------------------------------------
// sort + pull layer 1: one block (512 thr) per 128-node bucket.
//  (a) sort the bucket's records by local dst in LDS (hist+scan+scatter)
//  (b) write sorted records + per-node (start,end) for pull2 (coalesced)
//  (c) per-node-wave pull reading records from LDS, gathering rows straight
//      from eu/eit. 8 gathers in flight (latency depth doubled vs R5).
// ---------------------------------------------------------------------------
__global__ __launch_bounds__(512)
void sortpull1_kernel(const int* __restrict__ gcur, const int2* __restrict__ regions,
                      const float* __restrict__ eu, const float* __restrict__ eit,
                      int2* __restrict__ edge_sorted, int2* __restrict__ rs,
                      float* __restrict__ buf1) {
    __shared__ int2 srec[CAP];        // 16 KB sorted records
    __shared__ int cnt[128];          // hist, then scatter cursor
    __shared__ int excl[128];         // per-node start (local)
    __shared__ int scanbuf[128];
    const int t = threadIdx.x;
    const int b = blockIdx.x;
    const int node0 = b << BSH;
    const int ecnt = min(gcur[b], CAP);
    const long gbase = (long)b * CAP;

    if (t < 128) cnt[t] = 0;
    __syncthreads();

    // load raw records to registers + LDS histogram (1 scalar atomic/record)
    int2 recs[4];
#pragma unroll
    for (int k = 0; k < 4; ++k) {
        int i = k * 512 + t;
        if (i < ecnt) {
            recs[k] = regions[gbase + i];
            atomicAdd(&cnt[(recs[k].x >> 18) & 127], 1);
        }
    }
    __syncthreads();

    // scan of 128 counts
    if (t < 128) scanbuf[t] = cnt[t];
    __syncthreads();
    for (int d = 1; d < 128; d <<= 1) {
        int u = 0;
        if (t < 128 && t >= d) u = scanbuf[t - d];
        __syncthreads();
        if (t < 128) scanbuf[t] += u;
        __syncthreads();
    }
    if (t < 128) {
        excl[t] = scanbuf[t] - cnt[t];
        cnt[t] = scanbuf[t] - cnt[t];   // cursor = excl
    }
    __syncthreads();

    // scatter into sorted LDS array (clean src while at it)
#pragma unroll
    for (int k = 0; k < 4; ++k) {
        int i = k * 512 + t;
        if (i < ecnt) {
            int d = (recs[k].x >> 18) & 127;
            int p = atomicAdd(&cnt[d], 1);
            int2 o;
            o.x = recs[k].x & 0x3FFFF;
            o.y = recs[k].y;
            srec[p] = o;
        }
    }
    __syncthreads();
    // cnt[] now holds per-node END (exclusive), excl[] holds START

    // write-through for pull2: sorted records (coalesced) + (start,end) pairs
    for (int i = t; i < ecnt; i += 512) edge_sorted[gbase + i] = srec[i];
    if (t < 128) {
        int node = node0 + t;
        if (node < NNODES) {
            int2 p;
            p.x = (int)gbase + excl[t];
            p.y = (int)gbase + cnt[t];
            rs[node] = p;
        }
    }

    // per-node-wave pull from LDS records, 8 gathers in flight
    const int lane = t & 63;
    const int wv = t >> 6;                 // 0..7
#pragma unroll 1
    for (int j = 0; j < 16; ++j) {
        const int local = wv * 16 + j;
        const int node = node0 + local;
        if (node >= NNODES) break;         // wave-uniform
        int i = excl[local];
        const int iend = cnt[local];
        float a0 = 0.f, a1 = 0.f, a2 = 0.f, a3 = 0.f;
        for (; i + 7 < iend; i += 8) {
            int2 r0 = srec[i + 0], r1 = srec[i + 1], r2 = srec[i + 2], r3 = srec[i + 3];
            int2 r4 = srec[i + 4], r5 = srec[i + 5], r6 = srec[i + 6], r7 = srec[i + 7];
            const float* p0 = (r0.x < NUSERS) ? (eu + ((long)r0.x << 6)) : (eit + ((long)(r0.x - NUSERS) << 6));
            const float* p1 = (r1.x < NUSERS) ? (eu + ((long)r1.x << 6)) : (eit + ((long)(r1.x - NUSERS) << 6));
            const float* p2 = (r2.x < NUSERS) ? (eu + ((long)r2.x << 6)) : (eit + ((long)(r2.x - NUSERS) << 6));
            const float* p3 = (r3.x < NUSERS) ? (eu + ((long)r3.x << 6)) : (eit + ((long)(r3.x - NUSERS) << 6));
            const float* p4 = (r4.x < NUSERS) ? (eu + ((long)r4.x << 6)) : (eit + ((long)(r4.x - NUSERS) << 6));
            const float* p5 = (r5.x < NUSERS) ? (eu + ((long)r5.x << 6)) : (eit + ((long)(r5.x - NUSERS) << 6));
            const float* p6 = (r6.x < NUSERS) ? (eu + ((long)r6.x << 6)) : (eit + ((long)(r6.x - NUSERS) << 6));
            const float* p7 = (r7.x < NUSERS) ? (eu + ((long)r7.x << 6)) : (eit + ((long)(r7.x - NUSERS) << 6));
            float v0 = p0[lane], v1 = p1[lane], v2 = p2[lane], v3 = p3[lane];
            float v4 = p4[lane], v5 = p5[lane], v6 = p6[lane], v7 = p7[lane];
            a0 = fmaf(__int_as_float(r0.y), v0, a0);
            a1 = fmaf(__int_as_float(r1.y), v1, a1);
            a2 = fmaf(__int_as_float(r2.y), v2, a2);
            a3 = fmaf(__int_as_float(r3.y), v3, a3);
            a0 = fmaf(__int_as_float(r4.y), v4, a0);
            a1 = fmaf(__int_as_float(r5.y), v5, a1);
            a2 = fmaf(__int_as_float(r6.y), v6, a2);
            a3 = fmaf(__int_as_float(r7.y), v7, a3);
        }
        for (; i + 3 < iend; i += 4) {
            int2 r0 = srec[i + 0], r1 = srec[i + 1], r2 = srec[i + 2], r3 = srec[i + 3];
            const float* p0 = (r0.x < NUSERS) ? (eu + ((long)r0.x << 6)) : (eit + ((long)(r0.x - NUSERS) << 6));
            const float* p1 = (r1.x < NUSERS) ? (eu + ((long)r1.x << 6)) : (eit + ((long)(r1.x - NUSERS) << 6));
            const float* p2 = (r2.x < NUSERS) ? (eu + ((long)r2.x << 6)) : (eit + ((long)(r2.x - NUSERS) << 6));
            const float* p3 = (r3.x < NUSERS) ? (eu + ((long)r3.x << 6)) : (eit + ((long)(r3.x - NUSERS) << 6));
            a0 = fmaf(__int_as_float(r0.y), p0[lane], a0);
            a1 = fmaf(__int_as_float(r1.y), p1[lane], a1);
            a2 = fmaf(__int_as_float(r2.y), p2[lane], a2);
            a3 = fmaf(__int_as_float(r3.y), p3[lane], a3);
        }
        for (; i < iend; ++i) {
            int2 r = srec[i];
            const float* p = (r.x < NUSERS) ? (eu + ((long)r.x << 6)) : (eit + ((long)(r.x - NUSERS) << 6));
            a0 = fmaf(__int_as_float(r.y), p[lane], a0);
        }
        buf1[((long)node << 6) + lane] = fmaxf((a0 + a1) + (a2 + a3), 0.f);
    }
}

// ---------------------------------------------------------------------------
// pull layer 2: one wave per node, 8 gathers in flight (one 64B record line
// per batch). buf1 -> buf2, fused ReLU.
// ---------------------------------------------------------------------------
__global__ __launch_bounds__(256)
void pull2_kernel(const int2* __restrict__ rs,
                  const int2* __restrict__ edge_sorted,
                  const float* __restrict__ in_emb,
                  float* __restrict__ out_emb) {
    int lane = threadIdx.x & 63;
    int n = (int)((blockIdx.x * (long)blockDim.x + threadIdx.x) >> 6);  // node = wave id
    if (n >= NNODES) return;
    int2 be = rs[n];
    int i = be.x;
    const int e2 = be.y;
    float a0 = 0.f, a1 = 0.f, a2 = 0.f, a3 = 0.f;
    for (; i + 7 < e2; i += 8) {
        int2 r0 = edge_sorted[i + 0], r1 = edge_sorted[i + 1];
        int2 r2 = edge_sorted[i + 2], r3 = edge_sorted[i + 3];
        int2 r4 = edge_sorted[i + 4], r5 = edge_sorted[i + 5];
        int2 r6 = edge_sorted[i + 6], r7 = edge_sorted[i + 7];
        float v0 = in_emb[(long)r0.x * DIM + lane];
        float v1 = in_emb[(long)r1.x * DIM + lane];
        float v2 = in_emb[(long)r2.x * DIM + lane];
        float v3 = in_emb[(long)r3.x * DIM + lane];
        float v4 = in_emb[(long)r4.x * DIM + lane];
        float v5 = in_emb[(long)r5.x * DIM + lane];
        float v6 = in_emb[(long)r6.x * DIM + lane];
        float v7 = in_emb[(long)r7.x * DIM + lane];
        a0 = fmaf(__int_as_float(r0.y), v0, a0);
        a1 = fmaf(__int_as_float(r1.y), v1, a1);
        a2 = fmaf(__int_as_float(r2.y), v2, a2);
        a3 = fmaf(__int_as_float(r3.y), v3, a3);
        a0 = fmaf(__int_as_float(r4.y), v4, a0);
        a1 = fmaf(__int_as_float(r5.y), v5, a1);
        a2 = fmaf(__int_as_float(r6.y), v6, a2);
        a3 = fmaf(__int_as_float(r7.y), v7, a3);
    }
    for (; i + 3 < e2; i += 4) {
        int2 r0 = edge_sorted[i + 0], r1 = edge_sorted[i + 1];
        int2 r2 = edge_sorted[i + 2], r3 = edge_sorted[i + 3];
        float v0 = in_emb[(long)r0.x * DIM + lane];
        float v1 = in_emb[(long)r1.x * DIM + lane];
        float v2 = in_emb[(long)r2.x * DIM + lane];
        float v3 = in_emb[(long)r3.x * DIM + lane];
        a0 = fmaf(__int_as_float(r0.y), v0, a0);
        a1 = fmaf(__int_as_float(r1.y), v1, a1);
        a2 = fmaf(__int_as_float(r2.y), v2, a2);
        a3 = fmaf(__int_as_float(r3.y), v3, a3);
    }
    for (; i < e2; ++i) {
        int2 r = edge_sorted[i];
        a0 = fmaf(__int_as_float(r.y), in_emb[(long)r.x * DIM + lane], a0);
    }
    out_emb[(long)n * DIM + lane] = fmaxf((a0 + a1) + (a2 + a3), 0.f);
}

// ---------------------------------------------------------------------------
// epilogue GEMM, tile-staged (R5 structure, measured 38us). e0 rows come
// straight from eu/eit and the pass-through copy rows are emitted during
// staging. W-row loads amortized over 128 nodes per block.
// ---------------------------------------------------------------------------
__global__ __launch_bounds__(256)
void final_kernel(const float* __restrict__ eu, const float* __restrict__ eit,
                  const float* __restrict__ e1, const float* __restrict__ e2,
                  const float* __restrict__ W, const float* __restrict__ bias,
                  float* __restrict__ out) {
    __shared__ float4 As4[FT_ROWS * 16];                 // 128 rows x 64 floats = 32 KB
    const int t = threadIdx.x;
    const int lane = t & 63;
    const int wv = t >> 6;
    const long R0 = (long)blockIdx.x * FT_ROWS;

    float wreg[64];
#pragma unroll
    for (int k = 0; k < 16; ++k) {
        float4 wq = ((const float4*)(W + (long)lane * 64))[k];
        wreg[4 * k + 0] = wq.x; wreg[4 * k + 1] = wq.y;
        wreg[4 * k + 2] = wq.z; wreg[4 * k + 3] = wq.w;
    }
    float bj = bias[lane];

    const float4* g1 = (const float4*)(e1 + R0 * DIM);
    const float4* g2 = (const float4*)(e2 + R0 * DIM);
#pragma unroll
    for (int it = 0; it < 8; ++it) {
        int idx = it * 256 + t;                          // float4 index in tile
        long row = R0 + (idx >> 4);
        if (row < NNODES) {
            int q = idx & 15;
            // e0 from eu/eit (per-row select) + pass-through copy write
            const float4* g0;
            long co;
            if (row < NUSERS) {
                g0 = (const float4*)(eu + (row << 6));
                co = (long)NUSERS * DIM + (row << 6);
            } else {
                g0 = (const float4*)(eit + ((row - NUSERS) << 6));
                co = (long)2 * NUSERS * DIM + (long)NITEMS * DIM + ((row - NUSERS) << 6);
            }
            float4 v0 = g0[q];
            ((float4*)(out + co))[q] = v0;               // copy row
            float4 v1 = g1[idx], v2 = g2[idx];
            float4 s;
            s.x = v0.x + v1.x + v2.x; s.y = v0.y + v1.y + v2.y;
            s.z = v0.z + v1.z + v2.z; s.w = v0.w + v1.w + v2.w;
            As4[idx] = s;
        }
    }
    __syncthreads();

#pragma unroll 4
    for (int r = 0; r < 32; ++r) {
        int tr = wv * 32 + r;
        long row = R0 + tr;
        if (row >= NNODES) break;                        // wave-uniform
        const float4* a = As4 + tr * 16;
        float s0 = 0.f, s1 = 0.f;
#pragma unroll
        for (int k = 0; k < 16; ++k) {
            float4 v = a[k];                             // LDS broadcast
            s0 = fmaf(v.x, wreg[4 * k + 0], s0);
            s1 = fmaf(v.y, wreg[4 * k + 1], s1);
            s0 = fmaf(v.z, wreg[4 * k + 2], s0);
            s1 = fmaf(v.w, wreg[4 * k + 3], s1);
        }
        float val = fmaf(s0 + s1, (1.0f / 3.0f), bj);
        long o = (row < NUSERS) ? row * DIM
                                : (long)2 * NUSERS * DIM + (row - NUSERS) * DIM;
        out[o + lane] = val;
    }
}

extern "C" void kernel_launch(void* const* d_in, const int* in_sizes, int n_in,
                              void* d_out, int out_size, void* d_ws, size_t ws_size,
                              hipStream_t stream) {
    const int*   eidx = (const int*)d_in[0];     // (2, E) int
    const float* ew   = (const float*)d_in[1];   // (E,)
    const float* eu   = (const float*)d_in[2];   // (NUSERS, 64)
    const float* eit  = (const float*)d_in[3];   // (NITEMS, 64)
    const float* W    = (const float*)d_in[4];   // (64, 64)
    const float* bias = (const float*)d_in[5];   // (64,)
    float* out = (float*)d_out;

    const size_t nfeat = (size_t)NNODES * DIM;   // 9.6M floats
    float* buf1        = (float*)d_ws;                           // 38.4 MB
    float* buf2        = buf1 + nfeat;                           // 38.4 MB
    int2*  regions     = (int2*)(buf2 + nfeat);                  // 19.2 MB
    int2*  edge_sorted = regions + (long)NB * CAP;               // 19.2 MB
    int2*  rs          = edge_sorted + (long)NB * CAP;           // 1.2 MB
    int*   gcur        = (int*)(rs + NNODES);

    const int nodeWaveBlocks = (NNODES * 64 + 255) / 256;        // 37500

    hipMemsetAsync(gcur, 0, NB * sizeof(int), stream);

    // single-pass bucketed edge build
    bucket_kernel<<<ABLOCKS, 256, 0, stream>>>(eidx, ew, gcur, regions);

    // sort-in-LDS + layer-1 pull (8-deep gather pipeline)
    sortpull1_kernel<<<NB, 512, 0, stream>>>(gcur, regions, eu, eit,
                                             edge_sorted, rs, buf1);

    // layer 2: per-node-wave pull (8-deep gather pipeline)
    pull2_kernel<<<nodeWaveBlocks, 256, 0, stream>>>(rs, edge_sorted, buf1, buf2);

    // epilogue GEMM + pass-through copies
    final_kernel<<<FT_BLOCKS, 256, 0, stream>>>(eu, eit, buf1, buf2, W, bias, out);
}

// Round 9
// 379.274 us; speedup vs baseline: 1.8050x; 1.0781x over previous
//
#include <hip/hip_runtime.h>
#include <hip/hip_fp16.h>

#define NUSERS 100000
#define NITEMS 50000
#define NNODES (NUSERS + NITEMS)
#define DIM 64
#define NEDGE 2000000
#define FT_ROWS 128
#define FT_BLOCKS ((NNODES + FT_ROWS - 1) / FT_ROWS)   // 1172

// bucketed edge build
#define BSH 7                       // 128 dst nodes per bucket
#define NB ((NNODES + 127) >> BSH)  // 1172 buckets
#define CAP 2048                    // per-bucket region capacity (mean 1707, sd 41 -> 8.3 sigma)
#define CHUNK 4096                  // edges per bucket_kernel block (measured-good config)
#define ABLOCKS ((NEDGE + CHUNK - 1) / CHUNK)  // 489

// ---------------------------------------------------------------------------
// fp32 -> fp16 gather table (concat eu/eit). ~58 MB traffic, ~10 us.
// ---------------------------------------------------------------------------
__global__ void conv_kernel(const float* __restrict__ eu, const float* __restrict__ eit,
                            __half* __restrict__ tbl) {
    long i = (long)blockIdx.x * blockDim.x + threadIdx.x;   // float4 group
    const long total = (long)NNODES * DIM / 4;
    if (i >= total) return;
    const long ue = (long)NUSERS * DIM / 4;
    float4 v = (i < ue) ? ((const float4*)eu)[i] : ((const float4*)eit)[i - ue];
    __half2 h0 = __floats2half2_rn(v.x, v.y);
    __half2 h1 = __floats2half2_rn(v.z, v.w);
    ((__half2*)tbl)[2 * i + 0] = h0;
    ((__half2*)tbl)[2 * i + 1] = h1;
}

// ---------------------------------------------------------------------------
// Phase A: block-level counting sort of a 4096-edge chunk into 1172 coarse
// dst-buckets (dst>>7). Record = 8B: (src | (dst&127)<<18, w_bits).
// Unchanged (measured-good).
// ---------------------------------------------------------------------------
__global__ __launch_bounds__(256)
void bucket_kernel(const int* __restrict__ eidx, const float* __restrict__ ew,
                   int* __restrict__ gcur, int2* __restrict__ regions) {
    __shared__ int cursor_s[NB];          // histogram, then LDS staging cursor
    __shared__ int excl_s[NB];            // block-local exclusive offsets
    __shared__ int gbase_s[NB];           // reserved base inside bucket region
    __shared__ int scanbuf[256];
    __shared__ int2 stage[CHUNK];         // 32 KB
    __shared__ unsigned short sbkt[CHUNK];// 8 KB

    const int t = threadIdx.x;
    const int e0 = blockIdx.x * CHUNK;
    const int cnt_edges = min(CHUNK, NEDGE - e0);   // always multiple of 4

    for (int i = t; i < NB; i += 256) cursor_s[i] = 0;
    __syncthreads();

    // pass 1: load 16 edges/thread (int4/float4 coalesced), LDS histogram
    int2 recs[16];
    int bk[16];
    const int e4base = e0 >> 2;
#pragma unroll
    for (int k = 0; k < 4; ++k) {
        int g = k * 256 + t;                       // 4-edge group within chunk
        bool ok = (4 * g) < cnt_edges;
        int4 s4 = make_int4(0, 0, 0, 0), d4 = make_int4(0, 0, 0, 0);
        float4 w4 = make_float4(0.f, 0.f, 0.f, 0.f);
        if (ok) {
            int e4 = e4base + g;
            s4 = ((const int4*)eidx)[e4];
            d4 = ((const int4*)eidx)[(NEDGE >> 2) + e4];
            w4 = ((const float4*)ew)[e4];
        }
        int ss[4] = {s4.x, s4.y, s4.z, s4.w};
        int dd[4] = {d4.x, d4.y, d4.z, d4.w};
        float ww[4] = {w4.x, w4.y, w4.z, w4.w};
#pragma unroll
        for (int j = 0; j < 4; ++j) {
            int idx = 4 * k + j;
            if (ok) {
                int d = dd[j];
                int b = d >> BSH;
                bk[idx] = b;
                recs[idx].x = ss[j] | ((d & 127) << 18);   // src < 2^18
                recs[idx].y = __float_as_int(ww[j]);
                atomicAdd(&cursor_s[b], 1);
            } else {
                bk[idx] = -1;
            }
        }
    }
    __syncthreads();

    // block scan of the 1172 counts; thread t owns [5t, 5t+5)
    int myv[5];
    int tsum = 0;
    const int base_i = t * 5;
#pragma unroll
    for (int j = 0; j < 5; ++j) {
        int i = base_i + j;
        myv[j] = (i < NB) ? cursor_s[i] : 0;
        tsum += myv[j];
    }
    scanbuf[t] = tsum;
    __syncthreads();
    for (int d = 1; d < 256; d <<= 1) {
        int u = (t >= d) ? scanbuf[t - d] : 0;
        __syncthreads();
        scanbuf[t] += u;
        __syncthreads();
    }
    int run = scanbuf[t] - tsum;   // exclusive base of this thread's range
#pragma unroll
    for (int j = 0; j < 5; ++j) {
        int i = base_i + j;
        if (i < NB) {
            excl_s[i] = run;
            cursor_s[i] = run;     // becomes staging cursor
            if (myv[j] > 0) gbase_s[i] = atomicAdd(&gcur[i], myv[j]);
            run += myv[j];
        }
    }
    __syncthreads();

    // pass 2: counting-sort into LDS staging
#pragma unroll
    for (int k = 0; k < 16; ++k) {
        if (bk[k] >= 0) {
            int p = atomicAdd(&cursor_s[bk[k]], 1);
            stage[p] = recs[k];
            sbkt[p] = (unsigned short)bk[k];
        }
    }
    __syncthreads();

    // pass 3: coalesced write-out of per-bucket runs
    for (int i = t; i < cnt_edges; i += 256) {
        int b = sbkt[i];
        int gpos = gbase_s[b] + (i - excl_s[b]);
        if (gpos < CAP) regions[(long)b * CAP + gpos] = stage[i];
    }
}

// ---------------------------------------------------------------------------
// sort + pull layer 1: one block (512 thr) per 128-node bucket.
//  (a) sort the bucket's records by local dst in LDS (hist+scan+scatter)
//  (b) write sorted records + per-node (start,end) for pull2 (coalesced)
//  (c) per-node-wave pull reading records from LDS, gathering fp16 rows
//      from the concat table (no user/item select). 8 gathers in flight.
//      Writes buf1 as fp16 (halved write traffic).
// ---------------------------------------------------------------------------
__global__ __launch_bounds__(512)
void sortpull1_kernel(const int* __restrict__ gcur, const int2* __restrict__ regions,
                      const __half* __restrict__ tbl,
                      int2* __restrict__ edge_sorted, int2* __restrict__ rs,
                      __half* __restrict__ buf1h) {
    __shared__ int2 srec[CAP];        // 16 KB sorted records
    __shared__ int cnt[128];          // hist, then scatter cursor
    __shared__ int excl[128];         // per-node start (local)
    __shared__ int scanbuf[128];
    const int t = threadIdx.x;
    const int b = blockIdx.x;
    const int node0 = b << BSH;
    const int ecnt = min(gcur[b], CAP);
    const long gbase = (long)b * CAP;

    if (t < 128) cnt[t] = 0;
    __syncthreads();

    // load raw records to registers + LDS histogram (1 scalar atomic/record)
    int2 recs[4];
#pragma unroll
    for (int k = 0; k < 4; ++k) {
        int i = k * 512 + t;
        if (i < ecnt) {
            recs[k] = regions[gbase + i];
            atomicAdd(&cnt[(recs[k].x >> 18) & 127], 1);
        }
    }
    __syncthreads();

    // scan of 128 counts
    if (t < 128) scanbuf[t] = cnt[t];
    __syncthreads();
    for (int d = 1; d < 128; d <<= 1) {
        int u = 0;
        if (t < 128 && t >= d) u = scanbuf[t - d];
        __syncthreads();
        if (t < 128) scanbuf[t] += u;
        __syncthreads();
    }
    if (t < 128) {
        excl[t] = scanbuf[t] - cnt[t];
        cnt[t] = scanbuf[t] - cnt[t];   // cursor = excl
    }
    __syncthreads();

    // scatter into sorted LDS array (clean src while at it)
#pragma unroll
    for (int k = 0; k < 4; ++k) {
        int i = k * 512 + t;
        if (i < ecnt) {
            int d = (recs[k].x >> 18) & 127;
            int p = atomicAdd(&cnt[d], 1);
            int2 o;
            o.x = recs[k].x & 0x3FFFF;
            o.y = recs[k].y;
            srec[p] = o;
        }
    }
    __syncthreads();
    // cnt[] now holds per-node END (exclusive), excl[] holds START

    // write-through for pull2: sorted records (coalesced) + (start,end) pairs
    for (int i = t; i < ecnt; i += 512) edge_sorted[gbase + i] = srec[i];
    if (t < 128) {
        int node = node0 + t;
        if (node < NNODES) {
            int2 p;
            p.x = (int)gbase + excl[t];
            p.y = (int)gbase + cnt[t];
            rs[node] = p;
        }
    }

    // per-node-wave pull from LDS records, 8 fp16 gathers in flight
    const int lane = t & 63;
    const int wv = t >> 6;                 // 0..7
#pragma unroll 1
    for (int j = 0; j < 16; ++j) {
        const int local = wv * 16 + j;
        const int node = node0 + local;
        if (node >= NNODES) break;         // wave-uniform
        int i = excl[local];
        const int iend = cnt[local];
        float a0 = 0.f, a1 = 0.f, a2 = 0.f, a3 = 0.f;
        for (; i + 7 < iend; i += 8) {
            int2 r0 = srec[i + 0], r1 = srec[i + 1], r2 = srec[i + 2], r3 = srec[i + 3];
            int2 r4 = srec[i + 4], r5 = srec[i + 5], r6 = srec[i + 6], r7 = srec[i + 7];
            float v0 = __half2float(tbl[((long)r0.x << 6) + lane]);
            float v1 = __half2float(tbl[((long)r1.x << 6) + lane]);
            float v2 = __half2float(tbl[((long)r2.x << 6) + lane]);
            float v3 = __half2float(tbl[((long)r3.x << 6) + lane]);
            float v4 = __half2float(tbl[((long)r4.x << 6) + lane]);
            float v5 = __half2float(tbl[((long)r5.x << 6) + lane]);
            float v6 = __half2float(tbl[((long)r6.x << 6) + lane]);
            float v7 = __half2float(tbl[((long)r7.x << 6) + lane]);
            a0 = fmaf(__int_as_float(r0.y), v0, a0);
            a1 = fmaf(__int_as_float(r1.y), v1, a1);
            a2 = fmaf(__int_as_float(r2.y), v2, a2);
            a3 = fmaf(__int_as_float(r3.y), v3, a3);
            a0 = fmaf(__int_as_float(r4.y), v4, a0);
            a1 = fmaf(__int_as_float(r5.y), v5, a1);
            a2 = fmaf(__int_as_float(r6.y), v6, a2);
            a3 = fmaf(__int_as_float(r7.y), v7, a3);
        }
        for (; i + 3 < iend; i += 4) {
            int2 r0 = srec[i + 0], r1 = srec[i + 1], r2 = srec[i + 2], r3 = srec[i + 3];
            a0 = fmaf(__int_as_float(r0.y), __half2float(tbl[((long)r0.x << 6) + lane]), a0);
            a1 = fmaf(__int_as_float(r1.y), __half2float(tbl[((long)r1.x << 6) + lane]), a1);
            a2 = fmaf(__int_as_float(r2.y), __half2float(tbl[((long)r2.x << 6) + lane]), a2);
            a3 = fmaf(__int_as_float(r3.y), __half2float(tbl[((long)r3.x << 6) + lane]), a3);
        }
        for (; i < iend; ++i) {
            int2 r = srec[i];
            a0 = fmaf(__int_as_float(r.y), __half2float(tbl[((long)r.x << 6) + lane]), a0);
        }
        float rl = fmaxf((a0 + a1) + (a2 + a3), 0.f);
        buf1h[((long)node << 6) + lane] = __float2half_rn(rl);
    }
}

// ---------------------------------------------------------------------------
// pull layer 2: one wave per node, 8 fp16 gathers in flight. buf1h -> buf2h.
// ---------------------------------------------------------------------------
__global__ __launch_bounds__(256)
void pull2_kernel(const int2* __restrict__ rs,
                  const int2* __restrict__ edge_sorted,
                  const __half* __restrict__ in_emb,
                  __half* __restrict__ out_emb) {
    int lane = threadIdx.x & 63;
    int n = (int)((blockIdx.x * (long)blockDim.x + threadIdx.x) >> 6);  // node = wave id
    if (n >= NNODES) return;
    int2 be = rs[n];
    int i = be.x;
    const int e2 = be.y;
    float a0 = 0.f, a1 = 0.f, a2 = 0.f, a3 = 0.f;
    for (; i + 7 < e2; i += 8) {
        int2 r0 = edge_sorted[i + 0], r1 = edge_sorted[i + 1];
        int2 r2 = edge_sorted[i + 2], r3 = edge_sorted[i + 3];
        int2 r4 = edge_sorted[i + 4], r5 = edge_sorted[i + 5];
        int2 r6 = edge_sorted[i + 6], r7 = edge_sorted[i + 7];
        float v0 = __half2float(in_emb[((long)r0.x << 6) + lane]);
        float v1 = __half2float(in_emb[((long)r1.x << 6) + lane]);
        float v2 = __half2float(in_emb[((long)r2.x << 6) + lane]);
        float v3 = __half2float(in_emb[((long)r3.x << 6) + lane]);
        float v4 = __half2float(in_emb[((long)r4.x << 6) + lane]);
        float v5 = __half2float(in_emb[((long)r5.x << 6) + lane]);
        float v6 = __half2float(in_emb[((long)r6.x << 6) + lane]);
        float v7 = __half2float(in_emb[((long)r7.x << 6) + lane]);
        a0 = fmaf(__int_as_float(r0.y), v0, a0);
        a1 = fmaf(__int_as_float(r1.y), v1, a1);
        a2 = fmaf(__int_as_float(r2.y), v2, a2);
        a3 = fmaf(__int_as_float(r3.y), v3, a3);
        a0 = fmaf(__int_as_float(r4.y), v4, a0);
        a1 = fmaf(__int_as_float(r5.y), v5, a1);
        a2 = fmaf(__int_as_float(r6.y), v6, a2);
        a3 = fmaf(__int_as_float(r7.y), v7, a3);
    }
    for (; i + 3 < e2; i += 4) {
        int2 r0 = edge_sorted[i + 0], r1 = edge_sorted[i + 1];
        int2 r2 = edge_sorted[i + 2], r3 = edge_sorted[i + 3];
        a0 = fmaf(__int_as_float(r0.y), __half2float(in_emb[((long)r0.x << 6) + lane]), a0);
        a1 = fmaf(__int_as_float(r1.y), __half2float(in_emb[((long)r1.x << 6) + lane]), a1);
        a2 = fmaf(__int_as_float(r2.y), __half2float(in_emb[((long)r2.x << 6) + lane]), a2);
        a3 = fmaf(__int_as_float(r3.y), __half2float(in_emb[((long)r3.x << 6) + lane]), a3);
    }
    for (; i < e2; ++i) {
        int2 r = edge_sorted[i];
        a0 = fmaf(__int_as_float(r.y), __half2float(in_emb[((long)r.x << 6) + lane]), a0);
    }
    float rl = fmaxf((a0 + a1) + (a2 + a3), 0.f);
    out_emb[((long)n << 6) + lane] = __float2half_rn(rl);
}

// ---------------------------------------------------------------------------
// epilogue GEMM, tile-staged (measured structure). e0 from eu/eit fp32
// (pass-through copies bit-exact); e1/e2 read as fp16 (halved traffic).
// W-row loads amortized over 128 nodes per block.
// ---------------------------------------------------------------------------
__global__ __launch_bounds__(256)
void final_kernel(const float* __restrict__ eu, const float* __restrict__ eit,
                  const __half* __restrict__ e1, const __half* __restrict__ e2,
                  const float* __restrict__ W, const float* __restrict__ bias,
                  float* __restrict__ out) {
    __shared__ float4 As4[FT_ROWS * 16];                 // 128 rows x 64 floats = 32 KB
    const int t = threadIdx.x;
    const int lane = t & 63;
    const int wv = t >> 6;
    const long R0 = (long)blockIdx.x * FT_ROWS;

    float wreg[64];
#pragma unroll
    for (int k = 0; k < 16; ++k) {
        float4 wq = ((const float4*)(W + (long)lane * 64))[k];
        wreg[4 * k + 0] = wq.x; wreg[4 * k + 1] = wq.y;
        wreg[4 * k + 2] = wq.z; wreg[4 * k + 3] = wq.w;
    }
    float bj = bias[lane];

#pragma unroll
    for (int it = 0; it < 8; ++it) {
        int idx = it * 256 + t;                          // float4 index in tile
        long row = R0 + (idx >> 4);
        if (row < NNODES) {
            int q = idx & 15;
            // e0 from eu/eit (per-row select) + pass-through copy write
            const float4* g0;
            long co;
            if (row < NUSERS) {
                g0 = (const float4*)(eu + (row << 6));
                co = (long)NUSERS * DIM + (row << 6);
            } else {
                g0 = (const float4*)(eit + ((row - NUSERS) << 6));
                co = (long)2 * NUSERS * DIM + (long)NITEMS * DIM + ((row - NUSERS) << 6);
            }
            float4 v0 = g0[q];
            ((float4*)(out + co))[q] = v0;               // copy row
            const __half2* h1 = (const __half2*)(e1 + (row << 6));
            const __half2* h2 = (const __half2*)(e2 + (row << 6));
            float2 f1a = __half22float2(h1[2 * q]), f1b = __half22float2(h1[2 * q + 1]);
            float2 f2a = __half22float2(h2[2 * q]), f2b = __half22float2(h2[2 * q + 1]);
            float4 s;
            s.x = v0.x + f1a.x + f2a.x; s.y = v0.y + f1a.y + f2a.y;
            s.z = v0.z + f1b.x + f2b.x; s.w = v0.w + f1b.y + f2b.y;
            As4[idx] = s;
        }
    }
    __syncthreads();

#pragma unroll 4
    for (int r = 0; r < 32; ++r) {
        int tr = wv * 32 + r;
        long row = R0 + tr;
        if (row >= NNODES) break;                        // wave-uniform
        const float4* a = As4 + tr * 16;
        float s0 = 0.f, s1 = 0.f;
#pragma unroll
        for (int k = 0; k < 16; ++k) {
            float4 v = a[k];                             // LDS broadcast
            s0 = fmaf(v.x, wreg[4 * k + 0], s0);
            s1 = fmaf(v.y, wreg[4 * k + 1], s1);
            s0 = fmaf(v.z, wreg[4 * k + 2], s0);
            s1 = fmaf(v.w, wreg[4 * k + 3], s1);
        }
        float val = fmaf(s0 + s1, (1.0f / 3.0f), bj);
        long o = (row < NUSERS) ? row * DIM
                                : (long)2 * NUSERS * DIM + (row - NUSERS) * DIM;
        out[o + lane] = val;
    }
}

extern "C" void kernel_launch(void* const* d_in, const int* in_sizes, int n_in,
                              void* d_out, int out_size, void* d_ws, size_t ws_size,
                              hipStream_t stream) {
    const int*   eidx = (const int*)d_in[0];     // (2, E) int
    const float* ew   = (const float*)d_in[1];   // (E,)
    const float* eu   = (const float*)d_in[2];   // (NUSERS, 64)
    const float* eit  = (const float*)d_in[3];   // (NITEMS, 64)
    const float* W    = (const float*)d_in[4];   // (64, 64)
    const float* bias = (const float*)d_in[5];   // (64,)
    float* out = (float*)d_out;

    const size_t nfeat = (size_t)NNODES * DIM;   // 9.6M elements
    __half* tbl         = (__half*)d_ws;                         // 19.2 MB
    __half* buf1h       = tbl + nfeat;                           // 19.2 MB
    __half* buf2h       = buf1h + nfeat;                         // 19.2 MB
    int2*   regions     = (int2*)(buf2h + nfeat);                // 19.2 MB
    int2*   edge_sorted = regions + (long)NB * CAP;              // 19.2 MB
    int2*   rs          = edge_sorted + (long)NB * CAP;          // 1.2 MB
    int*    gcur        = (int*)(rs + NNODES);

    const int nodeWaveBlocks = (NNODES * 64 + 255) / 256;        // 37500
    const int convBlocks = (int)((nfeat / 4 + 255) / 256);       // 9375

    hipMemsetAsync(gcur, 0, NB * sizeof(int), stream);

    // fp16 gather table (concat of eu/eit)
    conv_kernel<<<convBlocks, 256, 0, stream>>>(eu, eit, tbl);

    // single-pass bucketed edge build
    bucket_kernel<<<ABLOCKS, 256, 0, stream>>>(eidx, ew, gcur, regions);

    // sort-in-LDS + layer-1 pull (fp16 gathers, fp16 buf1)
    sortpull1_kernel<<<NB, 512, 0, stream>>>(gcur, regions, tbl,
                                             edge_sorted, rs, buf1h);

    // layer 2: per-node-wave pull (fp16 gathers, fp16 buf2)
    pull2_kernel<<<nodeWaveBlocks, 256, 0, stream>>>(rs, edge_sorted, buf1h, buf2h);

    // epilogue GEMM + pass-through copies (e1/e2 fp16, e0 fp32 bit-exact)
    final_kernel<<<FT_BLOCKS, 256, 0, stream>>>(eu, eit, buf1h, buf2h, W, bias, out);
}

// Round 10
// 343.125 us; speedup vs baseline: 1.9951x; 1.1054x over previous
//
#include <hip/hip_runtime.h>
#include <hip/hip_fp16.h>

#define NUSERS 100000
#define NITEMS 50000
#define NNODES (NUSERS + NITEMS)
#define DIM 64
#define NEDGE 2000000
#define FT_ROWS 128
#define FT_BLOCKS ((NNODES + FT_ROWS - 1) / FT_ROWS)   // 1172

// bucketed edge build
#define BSH 7                       // 128 dst nodes per bucket
#define NB ((NNODES + 127) >> BSH)  // 1172 buckets
#define CAP 2048                    // per-bucket region capacity (mean 1707, sd 41 -> 8.3 sigma)
#define CHUNK 4096                  // edges per bucket block
#define ABLOCKS ((NEDGE + CHUNK - 1) / CHUNK)  // 489
#define CONVB ((NNODES * DIM / 4 + 511) / 512) // 4688 conv blocks (512 thr)

// ---------------------------------------------------------------------------
// Phase A (512 thr) + fused fp16-table conversion.
// blocks [0, ABLOCKS): counting sort of a 4096-edge chunk into 1172 coarse
//   dst-buckets (dst>>7). Record = 8B: (src | (dst&127)<<18, w_bits).
//   512 threads (was 256) -> 16 waves/CU for the atomic/scatter phases.
// blocks [ABLOCKS, ABLOCKS+CONVB): eu/eit fp32 -> fp16 concat table
//   (independent work, overlaps under bucket's latency stalls).
// ---------------------------------------------------------------------------
__global__ __launch_bounds__(512)
void bucketconv_kernel(const int* __restrict__ eidx, const float* __restrict__ ew,
                       int* __restrict__ gcur, int2* __restrict__ regions,
                       const float* __restrict__ eu, const float* __restrict__ eit,
                       __half* __restrict__ tbl) {
    const int t = threadIdx.x;

    if (blockIdx.x >= ABLOCKS) {
        // ---- conv part ----
        long i = (long)(blockIdx.x - ABLOCKS) * 512 + t;     // float4 group
        const long total = (long)NNODES * DIM / 4;
        if (i < total) {
            const long ue = (long)NUSERS * DIM / 4;
            float4 v = (i < ue) ? ((const float4*)eu)[i] : ((const float4*)eit)[i - ue];
            ((__half2*)tbl)[2 * i + 0] = __floats2half2_rn(v.x, v.y);
            ((__half2*)tbl)[2 * i + 1] = __floats2half2_rn(v.z, v.w);
        }
        return;
    }

    // ---- bucket part ----
    __shared__ int cursor_s[NB];          // histogram, then LDS staging cursor
    __shared__ int excl_s[NB];            // block-local exclusive offsets
    __shared__ int gbase_s[NB];           // reserved base inside bucket region
    __shared__ int scanbuf[512];
    __shared__ int2 stage[CHUNK];         // 32 KB
    __shared__ unsigned short sbkt[CHUNK];// 8 KB

    const int e0 = blockIdx.x * CHUNK;
    const int cnt_edges = min(CHUNK, NEDGE - e0);   // always multiple of 4

    for (int i = t; i < NB; i += 512) cursor_s[i] = 0;
    __syncthreads();

    // pass 1: load 8 edges/thread (int4/float4 coalesced), LDS histogram
    int2 recs[8];
    int bk[8];
    const int e4base = e0 >> 2;
#pragma unroll
    for (int k = 0; k < 2; ++k) {
        int g = k * 512 + t;                       // 4-edge group within chunk
        bool ok = (4 * g) < cnt_edges;
        int4 s4 = make_int4(0, 0, 0, 0), d4 = make_int4(0, 0, 0, 0);
        float4 w4 = make_float4(0.f, 0.f, 0.f, 0.f);
        if (ok) {
            int e4 = e4base + g;
            s4 = ((const int4*)eidx)[e4];
            d4 = ((const int4*)eidx)[(NEDGE >> 2) + e4];
            w4 = ((const float4*)ew)[e4];
        }
        int ss[4] = {s4.x, s4.y, s4.z, s4.w};
        int dd[4] = {d4.x, d4.y, d4.z, d4.w};
        float ww[4] = {w4.x, w4.y, w4.z, w4.w};
#pragma unroll
        for (int j = 0; j < 4; ++j) {
            int idx = 4 * k + j;
            if (ok) {
                int d = dd[j];
                int b = d >> BSH;
                bk[idx] = b;
                recs[idx].x = ss[j] | ((d & 127) << 18);   // src < 2^18
                recs[idx].y = __float_as_int(ww[j]);
                atomicAdd(&cursor_s[b], 1);
            } else {
                bk[idx] = -1;
            }
        }
    }
    __syncthreads();

    // block scan of the 1172 counts; thread t owns [3t, 3t+3)
    int myv[3];
    int tsum = 0;
    const int base_i = t * 3;
#pragma unroll
    for (int j = 0; j < 3; ++j) {
        int i = base_i + j;
        myv[j] = (i < NB) ? cursor_s[i] : 0;
        tsum += myv[j];
    }
    scanbuf[t] = tsum;
    __syncthreads();
    for (int d = 1; d < 512; d <<= 1) {
        int u = (t >= d) ? scanbuf[t - d] : 0;
        __syncthreads();
        scanbuf[t] += u;
        __syncthreads();
    }
    int run = scanbuf[t] - tsum;   // exclusive base of this thread's range
#pragma unroll
    for (int j = 0; j < 3; ++j) {
        int i = base_i + j;
        if (i < NB) {
            excl_s[i] = run;
            cursor_s[i] = run;     // becomes staging cursor
            if (myv[j] > 0) gbase_s[i] = atomicAdd(&gcur[i], myv[j]);
            run += myv[j];
        }
    }
    __syncthreads();

    // pass 2: counting-sort into LDS staging
#pragma unroll
    for (int k = 0; k < 8; ++k) {
        if (bk[k] >= 0) {
            int p = atomicAdd(&cursor_s[bk[k]], 1);
            stage[p] = recs[k];
            sbkt[p] = (unsigned short)bk[k];
        }
    }
    __syncthreads();

    // pass 3: coalesced write-out of per-bucket runs
    for (int i = t; i < cnt_edges; i += 512) {
        int b = sbkt[i];
        int gpos = gbase_s[b] + (i - excl_s[b]);
        if (gpos < CAP) regions[(long)b * CAP + gpos] = stage[i];
    }
}

// ---------------------------------------------------------------------------
// sort + pull layer 1: one block (512 thr) per 128-node bucket.
//  (a) sort the bucket's records by local dst in LDS (hist+scan+scatter)
//  (b) write sorted records + per-node (start,end) for pull2 (coalesced)
//  (c) HALF-WAVE pull: fp16 row = 128B = 32 lanes x __half2, so each gather
//      instruction serves TWO edges (one per half-wave). ceil(deg/8) memory
//      rounds of 4 instructions; tail via one exec-mask-predicated batch
//      (masked lanes issue no requests). Cross-half shfl_xor reduce.
// ---------------------------------------------------------------------------
__global__ __launch_bounds__(512)
void sortpull1_kernel(const int* __restrict__ gcur, const int2* __restrict__ regions,
                      const __half* __restrict__ tbl,
                      int2* __restrict__ edge_sorted, int2* __restrict__ rs,
                      __half* __restrict__ buf1h) {
    __shared__ int2 srec[CAP];        // 16 KB sorted records
    __shared__ int cnt[128];          // hist, then scatter cursor
    __shared__ int excl[128];         // per-node start (local)
    __shared__ int scanbuf[128];
    const int t = threadIdx.x;
    const int b = blockIdx.x;
    const int node0 = b << BSH;
    const int ecnt = min(gcur[b], CAP);
    const long gbase = (long)b * CAP;

    if (t < 128) cnt[t] = 0;
    __syncthreads();

    // load raw records to registers + LDS histogram (1 scalar atomic/record)
    int2 recs[4];
#pragma unroll
    for (int k = 0; k < 4; ++k) {
        int i = k * 512 + t;
        if (i < ecnt) {
            recs[k] = regions[gbase + i];
            atomicAdd(&cnt[(recs[k].x >> 18) & 127], 1);
        }
    }
    __syncthreads();

    // scan of 128 counts
    if (t < 128) scanbuf[t] = cnt[t];
    __syncthreads();
    for (int d = 1; d < 128; d <<= 1) {
        int u = 0;
        if (t < 128 && t >= d) u = scanbuf[t - d];
        __syncthreads();
        if (t < 128) scanbuf[t] += u;
        __syncthreads();
    }
    if (t < 128) {
        excl[t] = scanbuf[t] - cnt[t];
        cnt[t] = scanbuf[t] - cnt[t];   // cursor = excl
    }
    __syncthreads();

    // scatter into sorted LDS array (clean src while at it)
#pragma unroll
    for (int k = 0; k < 4; ++k) {
        int i = k * 512 + t;
        if (i < ecnt) {
            int d = (recs[k].x >> 18) & 127;
            int p = atomicAdd(&cnt[d], 1);
            int2 o;
            o.x = recs[k].x & 0x3FFFF;
            o.y = recs[k].y;
            srec[p] = o;
        }
    }
    __syncthreads();
    // cnt[] now holds per-node END (exclusive), excl[] holds START

    // write-through for pull2: sorted records (coalesced) + (start,end) pairs
    for (int i = t; i < ecnt; i += 512) edge_sorted[gbase + i] = srec[i];
    if (t < 128) {
        int node = node0 + t;
        if (node < NNODES) {
            int2 p;
            p.x = (int)gbase + excl[t];
            p.y = (int)gbase + cnt[t];
            rs[node] = p;
        }
    }

    // half-wave pull from LDS records
    const int lane = t & 63;
    const int wv = t >> 6;                 // 0..7
    const int half = lane >> 5;
    const int hl = lane & 31;
    const __half2* tb2 = (const __half2*)tbl;
#pragma unroll 1
    for (int j = 0; j < 16; ++j) {
        const int local = wv * 16 + j;
        const int node = node0 + local;
        if (node >= NNODES) break;         // wave-uniform
        int i = excl[local];
        const int iend = cnt[local];
        float ax = 0.f, ay = 0.f, bx = 0.f, by = 0.f;
        for (; i + 7 < iend; i += 8) {     // 4 instructions = 8 edges
#pragma unroll
            for (int u = 0; u < 4; ++u) {
                int2 r = srec[i + 2 * u + half];
                float w = __int_as_float(r.y);
                float2 v = __half22float2(tb2[((long)r.x << 5) + hl]);
                if (u & 1) { bx = fmaf(w, v.x, bx); by = fmaf(w, v.y, by); }
                else       { ax = fmaf(w, v.x, ax); ay = fmaf(w, v.y, ay); }
            }
        }
        if (i < iend) {                    // one predicated batch for the tail
#pragma unroll
            for (int u = 0; u < 4; ++u) {
                int idx = i + 2 * u + half;
                if (idx < iend) {
                    int2 r = srec[idx];
                    float w = __int_as_float(r.y);
                    float2 v = __half22float2(tb2[((long)r.x << 5) + hl]);
                    if (u & 1) { bx = fmaf(w, v.x, bx); by = fmaf(w, v.y, by); }
                    else       { ax = fmaf(w, v.x, ax); ay = fmaf(w, v.y, ay); }
                }
            }
        }
        float sx = ax + bx, sy = ay + by;
        sx += __shfl_xor(sx, 32);
        sy += __shfl_xor(sy, 32);
        if (half == 0) {
            ((__half2*)buf1h)[((long)node << 5) + hl] =
                __floats2half2_rn(fmaxf(sx, 0.f), fmaxf(sy, 0.f));
        }
    }
}

// ---------------------------------------------------------------------------
// pull layer 2: one block (512 thr) per bucket. Sorted records staged once
// into LDS (coalesced, removes the record round-trip), rs slice in LDS;
// half-wave gathers as above. buf1h -> buf2h, fused ReLU.
// ---------------------------------------------------------------------------
__global__ __launch_bounds__(512)
void pull2_kernel(const int* __restrict__ gcur, const int2* __restrict__ rs,
                  const int2* __restrict__ edge_sorted,
                  const __half* __restrict__ in_emb,
                  __half* __restrict__ out_emb) {
    __shared__ int2 srec[CAP];        // 16 KB
    __shared__ int2 rsl[128];
    const int t = threadIdx.x;
    const int b = blockIdx.x;
    const int node0 = b << BSH;
    const int ecnt = min(gcur[b], CAP);
    const long gbase = (long)b * CAP;

    for (int i = t; i < ecnt; i += 512) srec[i] = edge_sorted[gbase + i];
    if (t < 128) {
        int node = node0 + t;
        rsl[t] = (node < NNODES) ? rs[node] : make_int2(0, 0);
    }
    __syncthreads();

    const int lane = t & 63;
    const int wv = t >> 6;
    const int half = lane >> 5;
    const int hl = lane & 31;
    const __half2* tb2 = (const __half2*)in_emb;
#pragma unroll 1
    for (int j = 0; j < 16; ++j) {
        const int local = wv * 16 + j;
        const int node = node0 + local;
        if (node >= NNODES) break;         // wave-uniform
        int i = rsl[local].x - (int)gbase;
        const int iend = rsl[local].y - (int)gbase;
        float ax = 0.f, ay = 0.f, bx = 0.f, by = 0.f;
        for (; i + 7 < iend; i += 8) {
#pragma unroll
            for (int u = 0; u < 4; ++u) {
                int2 r = srec[i + 2 * u + half];
                float w = __int_as_float(r.y);
                float2 v = __half22float2(tb2[((long)r.x << 5) + hl]);
                if (u & 1) { bx = fmaf(w, v.x, bx); by = fmaf(w, v.y, by); }
                else       { ax = fmaf(w, v.x, ax); ay = fmaf(w, v.y, ay); }
            }
        }
        if (i < iend) {
#pragma unroll
            for (int u = 0; u < 4; ++u) {
                int idx = i + 2 * u + half;
                if (idx < iend) {
                    int2 r = srec[idx];
                    float w = __int_as_float(r.y);
                    float2 v = __half22float2(tb2[((long)r.x << 5) + hl]);
                    if (u & 1) { bx = fmaf(w, v.x, bx); by = fmaf(w, v.y, by); }
                    else       { ax = fmaf(w, v.x, ax); ay = fmaf(w, v.y, ay); }
                }
            }
        }
        float sx = ax + bx, sy = ay + by;
        sx += __shfl_xor(sx, 32);
        sy += __shfl_xor(sy, 32);
        if (half == 0) {
            ((__half2*)out_emb)[((long)node << 5) + hl] =
                __floats2half2_rn(fmaxf(sx, 0.f), fmaxf(sy, 0.f));
        }
    }
}

// ---------------------------------------------------------------------------
// epilogue GEMM, tile-staged (measured structure). e0 from eu/eit fp32
// (pass-through copies bit-exact); e1/e2 read as fp16.
// W-row loads amortized over 128 nodes per block.
// ---------------------------------------------------------------------------
__global__ __launch_bounds__(256)
void final_kernel(const float* __restrict__ eu, const float* __restrict__ eit,
                  const __half* __restrict__ e1, const __half* __restrict__ e2,
                  const float* __restrict__ W, const float* __restrict__ bias,
                  float* __restrict__ out) {
    __shared__ float4 As4[FT_ROWS * 16];                 // 128 rows x 64 floats = 32 KB
    const int t = threadIdx.x;
    const int lane = t & 63;
    const int wv = t >> 6;
    const long R0 = (long)blockIdx.x * FT_ROWS;

    float wreg[64];
#pragma unroll
    for (int k = 0; k < 16; ++k) {
        float4 wq = ((const float4*)(W + (long)lane * 64))[k];
        wreg[4 * k + 0] = wq.x; wreg[4 * k + 1] = wq.y;
        wreg[4 * k + 2] = wq.z; wreg[4 * k + 3] = wq.w;
    }
    float bj = bias[lane];

#pragma unroll
    for (int it = 0; it < 8; ++it) {
        int idx = it * 256 + t;                          // float4 index in tile
        long row = R0 + (idx >> 4);
        if (row < NNODES) {
            int q = idx & 15;
            // e0 from eu/eit (per-row select) + pass-through copy write
            const float4* g0;
            long co;
            if (row < NUSERS) {
                g0 = (const float4*)(eu + (row << 6));
                co = (long)NUSERS * DIM + (row << 6);
            } else {
                g0 = (const float4*)(eit + ((row - NUSERS) << 6));
                co = (long)2 * NUSERS * DIM + (long)NITEMS * DIM + ((row - NUSERS) << 6);
            }
            float4 v0 = g0[q];
            ((float4*)(out + co))[q] = v0;               // copy row
            const __half2* h1 = (const __half2*)(e1 + (row << 6));
            const __half2* h2 = (const __half2*)(e2 + (row << 6));
            float2 f1a = __half22float2(h1[2 * q]), f1b = __half22float2(h1[2 * q + 1]);
            float2 f2a = __half22float2(h2[2 * q]), f2b = __half22float2(h2[2 * q + 1]);
            float4 s;
            s.x = v0.x + f1a.x + f2a.x; s.y = v0.y + f1a.y + f2a.y;
            s.z = v0.z + f1b.x + f2b.x; s.w = v0.w + f1b.y + f2b.y;
            As4[idx] = s;
        }
    }
    __syncthreads();

#pragma unroll 4
    for (int r = 0; r < 32; ++r) {
        int tr = wv * 32 + r;
        long row = R0 + tr;
        if (row >= NNODES) break;                        // wave-uniform
        const float4* a = As4 + tr * 16;
        float s0 = 0.f, s1 = 0.f;
#pragma unroll
        for (int k = 0; k < 16; ++k) {
            float4 v = a[k];                             // LDS broadcast
            s0 = fmaf(v.x, wreg[4 * k + 0], s0);
            s1 = fmaf(v.y, wreg[4 * k + 1], s1);
            s0 = fmaf(v.z, wreg[4 * k + 2], s0);
            s1 = fmaf(v.w, wreg[4 * k + 3], s1);
        }
        float val = fmaf(s0 + s1, (1.0f / 3.0f), bj);
        long o = (row < NUSERS) ? row * DIM
                                : (long)2 * NUSERS * DIM + (row - NUSERS) * DIM;
        out[o + lane] = val;
    }
}

extern "C" void kernel_launch(void* const* d_in, const int* in_sizes, int n_in,
                              void* d_out, int out_size, void* d_ws, size_t ws_size,
                              hipStream_t stream) {
    const int*   eidx = (const int*)d_in[0];     // (2, E) int
    const float* ew   = (const float*)d_in[1];   // (E,)
    const float* eu   = (const float*)d_in[2];   // (NUSERS, 64)
    const float* eit  = (const float*)d_in[3];   // (NITEMS, 64)
    const float* W    = (const float*)d_in[4];   // (64, 64)
    const float* bias = (const float*)d_in[5];   // (64,)
    float* out = (float*)d_out;

    const size_t nfeat = (size_t)NNODES * DIM;   // 9.6M elements
    __half* tbl         = (__half*)d_ws;                         // 19.2 MB
    __half* buf1h       = tbl + nfeat;                           // 19.2 MB
    __half* buf2h       = buf1h + nfeat;                         // 19.2 MB
    int2*   regions     = (int2*)(buf2h + nfeat);                // 19.2 MB
    int2*   edge_sorted = regions + (long)NB * CAP;              // 19.2 MB
    int2*   rs          = edge_sorted + (long)NB * CAP;          // 1.2 MB
    int*    gcur        = (int*)(rs + NNODES);

    hipMemsetAsync(gcur, 0, NB * sizeof(int), stream);

    // bucketed edge build + fp16 table conversion in one dispatch
    bucketconv_kernel<<<ABLOCKS + CONVB, 512, 0, stream>>>(eidx, ew, gcur, regions,
                                                           eu, eit, tbl);

    // sort-in-LDS + layer-1 pull (half-wave fp16 gathers)
    sortpull1_kernel<<<NB, 512, 0, stream>>>(gcur, regions, tbl,
                                             edge_sorted, rs, buf1h);

    // layer 2: bucket-block pull, LDS records, half-wave fp16 gathers
    pull2_kernel<<<NB, 512, 0, stream>>>(gcur, rs, edge_sorted, buf1h, buf2h);

    // epilogue GEMM + pass-through copies (e1/e2 fp16, e0 fp32 bit-exact)
    final_kernel<<<FT_BLOCKS, 256, 0, stream>>>(eu, eit, buf1h, buf2h, W, bias, out);
}